// Round 16
// baseline (122.842 us; speedup 1.0000x reference)
//
#include <hip/hip_runtime.h>
#include <stdint.h>
#include <stddef.h>

#define NG 128
#define SEQ 512
#define CIN 64
#define HID 128
#define NROWS (NG*SEQ)   // 65536
#define KLEN 256
#define YS 272           // ylds/ulds row stride (bytes): 256 data + 16 pad (bank skew)

typedef __attribute__((ext_vector_type(8))) short v8s;
typedef __attribute__((ext_vector_type(4))) short v4s;
typedef __attribute__((ext_vector_type(4))) float v4f;
typedef __attribute__((ext_vector_type(2))) unsigned v2u;
typedef unsigned short u16;

__device__ __forceinline__ float b2f(u16 u) {
    union { unsigned int i; float f; } v; v.i = ((unsigned int)u) << 16; return v.f;
}
__device__ __forceinline__ u16 f2b(float f) {
    unsigned int x = __float_as_uint(f);
    unsigned int r = (x + 0x7fffu + ((x >> 16) & 1u)) >> 16;
    return (u16)r;
}
// packed f32x2 -> bf16x2 (RNE), single HW inst
__device__ __forceinline__ unsigned cvtpk(float lo, float hi) {
    unsigned r;
    asm("v_cvt_pk_bf16_f32 %0, %1, %2" : "=v"(r) : "v"(lo), "v"(hi));
    return r;
}
// raw v_exp_f32 (R7-validated: passed at absmax 0.015625)
__device__ __forceinline__ float exp2a(float x) {
#if __has_builtin(__builtin_amdgcn_exp2f)
    return __builtin_amdgcn_exp2f(x);
#else
    float r;
    asm("v_exp_f32 %0, %1\n\ts_nop 1" : "=v"(r) : "v"(x));
    return r;
#endif
}
// fast sigmoid: v_rcp instead of IEEE divide (~1 ulp, pre-bf16-quantization; R12-validated)
__device__ __forceinline__ float sigf(float x) {
    return __builtin_amdgcn_rcpf(1.0f + __expf(-x));
}

// ---------------- prep: f32 -> bf16 weights + per-channel tau table ----------------
__global__ void prep_kernel(const float* __restrict__ Wp, const float* __restrict__ Wi,
                            const float* __restrict__ Wo, const float* __restrict__ log_tau,
                            u16* __restrict__ Wpbf, u16* __restrict__ Wibf,
                            u16* __restrict__ Wobf, float4* __restrict__ tab) {
    int stride = gridDim.x * blockDim.x;
    int t0 = blockIdx.x * blockDim.x + threadIdx.x;
    for (int i = t0; i < 3 * 2 * HID * HID; i += stride) Wibf[i] = f2b(Wi[i]);
    for (int i = t0; i < 3 * HID * HID; i += stride) Wobf[i] = f2b(Wo[i]);
    for (int i = t0; i < HID * CIN; i += stride) Wpbf[i] = f2b(Wp[i]);
    if (t0 < 3 * HID) {
        float tau = fmaxf(expf(log_tau[t0]), 0.001f);
        float lq = -(1.0f / tau) * 1.44269504089f;
        float q = exp2f(lq);
        float S = (q < 0.9999999f) ? (1.0f - exp2f(256.0f * lq)) / (1.0f - q) : 256.0f;
        tab[t0] = make_float4(lq, q, exp2f(-lq), 1.0f / (S + 1e-8f));
    }
}

// ---------------- proj: h = x @ Wp^T + bp -> actR[g*512+l][c] (row-major) ----------------
// XCD swizzle: XCD k owns graphs [k*16, (k+1)*16) — matches chunkh/fused/mean.
__global__ __launch_bounds__(256, 4) void proj_kernel(const float* __restrict__ x,
                                                      const u16* __restrict__ Wp,
                                                      const float* __restrict__ bp,
                                                      u16* __restrict__ actR) {
    const int wave = threadIdx.x >> 6, lane = threadIdx.x & 63;
    const int fr = lane & 15, kgrp = lane >> 4;
    const int swz = (blockIdx.x & 7) * 128 + (blockIdx.x >> 3);   // XCD g-affinity
    const int l = swz * 64 + wave * 16 + fr;           // this lane's output row
    const int n0 = kgrp * 4;                           // channel quad base (per nt add nt*16)

    v4f acc[8];
#pragma unroll
    for (int nt = 0; nt < 8; ++nt) acc[nt] = (v4f){0.f, 0.f, 0.f, 0.f};

#pragma unroll
    for (int ks = 0; ks < 2; ++ks) {
        const float* ap = x + (size_t)l * CIN + ks * 32 + kgrp * 8;
        float4 f0 = *(const float4*)ap;
        float4 f1 = *(const float4*)(ap + 4);
        union { unsigned u[4]; v8s s; } bf;
        bf.u[0] = cvtpk(f0.x, f0.y); bf.u[1] = cvtpk(f0.z, f0.w);
        bf.u[2] = cvtpk(f1.x, f1.y); bf.u[3] = cvtpk(f1.z, f1.w);
#pragma unroll
        for (int nt = 0; nt < 8; ++nt) {
            v8s a = *(const v8s*)(Wp + (size_t)(nt * 16 + fr) * CIN + ks * 32 + kgrp * 8);
            acc[nt] = __builtin_amdgcn_mfma_f32_16x16x32_bf16(a, bf.s, acc[nt], 0, 0, 0);
        }
    }
#pragma unroll
    for (int nt = 0; nt < 8; ++nt) {
        const int c = nt * 16 + n0;
        float4 bb = *(const float4*)(bp + c);
        union { unsigned u[2]; v4s s; } pk;
        pk.u[0] = cvtpk(acc[nt][0] + bb.x, acc[nt][1] + bb.y);
        pk.u[1] = cvtpk(acc[nt][2] + bb.z, acc[nt][3] + bb.w);
        *(v4s*)(actR + (size_t)l * HID + c) = pk.s;
    }
}

// ---------------- chunkh: exclusive-prefix carries Pre[g][64][128] ----------------
// XCD swizzle: g = (b&7)*16 + b>>3 — same g-ownership as fused.
__global__ __launch_bounds__(512) void chunkh_kernel(const u16* __restrict__ actR,
                                                     float* __restrict__ Pre,
                                                     const float4* __restrict__ tab) {
    __shared__ float2 t8[8][64];
    const int tid = threadIdx.x;
    const int g = (blockIdx.x & 7) * 16 + (blockIdx.x >> 3);
    const int cp = tid & 63, sc = tid >> 6;
    const int c0 = 2 * cp;
    const unsigned* x32 = (const unsigned*)(actR + (size_t)g * (SEQ * HID));
    float4 tv0 = tab[c0], tv1 = tab[c0 + 1];
    float q0 = tv0.y, q1 = tv1.y;
    float sp0 = exp2a((float)(sc * 64) * tv0.x);
    float sp1 = exp2a((float)(sc * 64) * tv1.x);
    float h0[8], h1[8];
#pragma unroll
    for (int s = 0; s < 8; ++s) {
        float a0 = 0.f, a1 = 0.f;
#pragma unroll
        for (int j = 0; j < 8; ++j) {
            unsigned xv = x32[(size_t)(sc * 64 + s * 8 + j) * 64 + cp];
            a0 += sp0 * b2f((u16)(xv & 0xffff));
            a1 += sp1 * b2f((u16)(xv >> 16));
            sp0 *= q0; sp1 *= q1;
        }
        h0[s] = a0; h1[s] = a1;
    }
    float T0 = 0.f, T1 = 0.f;
#pragma unroll
    for (int s = 0; s < 8; ++s) { T0 += h0[s]; T1 += h1[s]; }
    t8[sc][cp] = make_float2(T0, T1);
    __syncthreads();
    float b0 = 0.f, b1 = 0.f;
    for (int s = 0; s < sc; ++s) { float2 v = t8[s][cp]; b0 += v.x; b1 += v.y; }
    float* PreG = Pre + (size_t)g * 64 * HID;
#pragma unroll
    for (int s = 0; s < 8; ++s) {
        *(float2*)(PreG + (size_t)(sc * 8 + s) * HID + c0) = make_float2(b0, b1);
        b0 += h0[s]; b1 += h1[s];
    }
}

// ---------------- fused: scan -> GEMM1/GLU -> GEMM2 -> LN -> actR ----------------
// XCD swizzle: XCD k owns all 8 tiles of graphs [k*16, (k+1)*16) -> actR[g]/Pre[g] L2-resident.
__global__ __launch_bounds__(512, 4) void fused_kernel(const u16* __restrict__ actR,
                                                       const float* __restrict__ Pre,
                                                       const u16* __restrict__ Win,
                                                       const u16* __restrict__ Wout,
                                                       const float* __restrict__ b_in,
                                                       const float* __restrict__ b_out,
                                                       const float* __restrict__ gamma,
                                                       const float* __restrict__ beta,
                                                       const float4* __restrict__ tab,
                                                       u16* __restrict__ actRout) {
    __shared__ __align__(16) char ylds[64 * YS];   // y, [l][c] bf16, XOR-swizzled, padded stride
    __shared__ __align__(16) char ulds[64 * YS];   // u, same layout
    __shared__ float2 red[8][64];
    __shared__ float2 murstd[64];
    const int tid = threadIdx.x;
    const int swz = (blockIdx.x & 7) * 128 + (blockIdx.x >> 3);   // XCD g-affinity
    const int g = swz >> 3, tile = swz & 7;
    const int r0 = tile * 64;
    const size_t gbase = (size_t)g * (SEQ * HID);

    // ---- scan: thread (cp, sc) -> channels {2cp,2cp+1}, rows [r0+sc*8, +8) ----
    {
        const int cp = tid & 63, sc = tid >> 6;
        const int c0 = 2 * cp;
        const int l0 = r0 + sc * 8;
        const bool hasd = (r0 >= KLEN);            // block-uniform
        const unsigned* x32 = (const unsigned*)(actR + gbase);
        unsigned xw[8], xdw[8];
#pragma unroll
        for (int j = 0; j < 8; ++j) xw[j] = x32[(size_t)(l0 + j) * 64 + cp];
        if (hasd) {
#pragma unroll
            for (int j = 0; j < 8; ++j) xdw[j] = x32[(size_t)(l0 - KLEN + j) * 64 + cp];
        }
        const float* PreG = Pre + ((size_t)g * 64 + (l0 >> 3)) * HID + c0;
        float2 pin = *(const float2*)PreG;
        float2 pdin = hasd ? *(const float2*)(PreG - 32 * HID) : make_float2(0.f, 0.f);
        float4 tv0 = tab[c0], tv1 = tab[c0 + 1];
        float P[2]    = { pin.x, pin.y };
        float Pd[2]   = { pdin.x, pdin.y };
        float q[2]    = { tv0.y, tv1.y };
        float qinv[2] = { tv0.z, tv1.z };
        float sp[2], w[2], spd[2];
        sp[0] = exp2a((float)l0 * tv0.x);
        sp[1] = exp2a((float)l0 * tv1.x);
        w[0] = exp2a((float)(255 - l0) * tv0.x) * tv0.w;
        w[1] = exp2a((float)(255 - l0) * tv1.x) * tv1.w;
        spd[0] = hasd ? exp2a((float)(l0 - KLEN) * tv0.x) : 0.f;
        spd[1] = hasd ? exp2a((float)(l0 - KLEN) * tv1.x) : 0.f;
#pragma unroll
        for (int j = 0; j < 8; ++j) {
            const int lt = sc * 8 + j;
            float y0, y1;
            {
                P[0] += sp[0] * b2f((u16)(xw[j] & 0xffff)); sp[0] *= q[0];
                P[1] += sp[1] * b2f((u16)(xw[j] >> 16));    sp[1] *= q[1];
                float Po0 = 0.f, Po1 = 0.f;
                if (hasd) {
                    Pd[0] += spd[0] * b2f((u16)(xdw[j] & 0xffff)); spd[0] *= q[0]; Po0 = Pd[0];
                    Pd[1] += spd[1] * b2f((u16)(xdw[j] >> 16));    spd[1] *= q[1]; Po1 = Pd[1];
                }
                y0 = w[0] * (P[0] - Po0); w[0] *= qinv[0];
                y1 = w[1] * (P[1] - Po1); w[1] *= qinv[1];
            }
            *(unsigned*)(ylds + lt * YS + ((4 * cp) ^ ((lt & 7) << 4))) = cvtpk(y0, y1);
        }
    }

    const int wave = tid >> 6, lane = tid & 63;
    const int fr = lane & 15, kgrp = lane >> 4;
    const int n0 = wave * 16 + kgrp * 4;     // this lane's channel quad (GEMM out dim)

    // weight-stationary fragments (A-operands): Win a-rows, g-rows, Wout rows
    v8s b1a[4], b1g[4], b2[4];
#pragma unroll
    for (int ks = 0; ks < 4; ++ks) {
        b1a[ks] = *(const v8s*)(Win + (size_t)(wave * 16 + fr) * HID + ks * 32 + kgrp * 8);
        b1g[ks] = *(const v8s*)(Win + (size_t)((wave + 8) * 16 + fr) * HID + ks * 32 + kgrp * 8);
        b2[ks]  = *(const v8s*)(Wout + (size_t)(wave * 16 + fr) * HID + ks * 32 + kgrp * 8);
    }
    const float4 ba4 = *(const float4*)(b_in + n0);
    const float4 bg4 = *(const float4*)(b_in + HID + n0);
    const float4 bo4 = *(const float4*)(b_out + n0);

    __syncthreads();   // S1: ylds ready

    // ---- GEMM1 swapped (D[n][l]) + in-reg GLU -> ulds b64 packed ----
    __builtin_amdgcn_s_setprio(1);   // T5: favor compute-phase waves vs other blocks' scan phase
#pragma unroll
    for (int rt = 0; rt < 4; ++rt) {
        const int arow = rt * 16 + fr;
        const char* abase = ylds + arow * YS;
        const int asw = (arow & 7) << 4;
        v8s af[4];
#pragma unroll
        for (int ks = 0; ks < 4; ++ks)
            af[ks] = *(const v8s*)(abase + ((ks * 64 + kgrp * 16) ^ asw));
        v4f a0 = (v4f){0.f, 0.f, 0.f, 0.f}, a1 = (v4f){0.f, 0.f, 0.f, 0.f};
#pragma unroll
        for (int ks = 0; ks < 4; ++ks) {
            a0 = __builtin_amdgcn_mfma_f32_16x16x32_bf16(b1a[ks], af[ks], a0, 0, 0, 0);
            a1 = __builtin_amdgcn_mfma_f32_16x16x32_bf16(b1g[ks], af[ks], a1, 0, 0, 0);
        }
        float u0 = (a0[0] + ba4.x) * sigf(a1[0] + bg4.x);
        float u1 = (a0[1] + ba4.y) * sigf(a1[1] + bg4.y);
        float u2 = (a0[2] + ba4.z) * sigf(a1[2] + bg4.z);
        float u3 = (a0[3] + ba4.w) * sigf(a1[3] + bg4.w);
        v2u pk;
        pk[0] = cvtpk(u0, u1); pk[1] = cvtpk(u2, u3);
        *(v2u*)(ulds + arow * YS + ((2 * n0) ^ asw)) = pk;
    }
    __builtin_amdgcn_s_setprio(0);
    __syncthreads();   // S2: ulds ready

    // ---- GEMM2 swapped: acc2[rt][r] = z at (n = n0+r, l = rt*16+fr) ----
    v4f acc2[4];
#pragma unroll
    for (int rt = 0; rt < 4; ++rt) acc2[rt] = (v4f){0.f, 0.f, 0.f, 0.f};
    __builtin_amdgcn_s_setprio(1);
#pragma unroll
    for (int rt = 0; rt < 4; ++rt) {
        const int arow = rt * 16 + fr;
        const char* abase = ulds + arow * YS;
        const int asw = (arow & 7) << 4;
#pragma unroll
        for (int ks = 0; ks < 4; ++ks) {
            v8s af = *(const v8s*)(abase + ((ks * 64 + kgrp * 16) ^ asw));
            acc2[rt] = __builtin_amdgcn_mfma_f32_16x16x32_bf16(b2[ks], af, acc2[rt], 0, 0, 0);
        }
    }
    __builtin_amdgcn_s_setprio(0);
    // residual + LN partials (per-lane values are row-aligned now)
#pragma unroll
    for (int rt = 0; rt < 4; ++rt) {
        const int l = rt * 16 + fr;
        v4s yv = *(const v4s*)(ylds + l * YS + ((2 * n0) ^ ((l & 7) << 4)));
        float z0 = acc2[rt][0] + bo4.x + b2f((u16)yv[0]);
        float z1 = acc2[rt][1] + bo4.y + b2f((u16)yv[1]);
        float z2 = acc2[rt][2] + bo4.z + b2f((u16)yv[2]);
        float z3 = acc2[rt][3] + bo4.w + b2f((u16)yv[3]);
        acc2[rt][0] = z0; acc2[rt][1] = z1; acc2[rt][2] = z2; acc2[rt][3] = z3;
        float s = z0 + z1 + z2 + z3;
        float sq = z0 * z0 + z1 * z1 + z2 * z2 + z3 * z3;
        s += __shfl_xor(s, 16); sq += __shfl_xor(sq, 16);
        s += __shfl_xor(s, 32); sq += __shfl_xor(sq, 32);
        if (lane < 16) red[wave][l] = make_float2(s, sq);
    }
    __syncthreads();   // S3: red ready

    if (tid < 64) {
        float a = 0.f, b = 0.f;
#pragma unroll
        for (int j = 0; j < 8; ++j) { float2 v = red[j][tid]; a += v.x; b += v.y; }
        float mu = a * (1.0f / 128.0f);
        float var = b * (1.0f / 128.0f) - mu * mu;
        murstd[tid] = make_float2(mu, rsqrtf(var + 1e-5f));
    }
    __syncthreads();   // S4: murstd ready

    // epilogue: normalize + packed coalesced b64 store to actRout[l][c]
    const float4 gm4 = *(const float4*)(gamma + n0);
    const float4 bt4 = *(const float4*)(beta + n0);
#pragma unroll
    for (int rt = 0; rt < 4; ++rt) {
        const int l = rt * 16 + fr;
        float2 ms = murstd[l];
        float o0 = (acc2[rt][0] - ms.x) * ms.y * gm4.x + bt4.x;
        float o1 = (acc2[rt][1] - ms.x) * ms.y * gm4.y + bt4.y;
        float o2 = (acc2[rt][2] - ms.x) * ms.y * gm4.z + bt4.z;
        float o3 = (acc2[rt][3] - ms.x) * ms.y * gm4.w + bt4.w;
        union { unsigned u[2]; v4s s; } pk;
        pk.u[0] = cvtpk(o0, o1); pk.u[1] = cvtpk(o2, o3);
        *(v4s*)(actRout + gbase + (size_t)(r0 + l) * HID + n0) = pk.s;
    }
}

// ---------------- final mean over L (coalesced [l][c] reads) ----------------
// XCD swizzle: same g-ownership as fused (last layer's actR is L2-hot).
__global__ __launch_bounds__(512) void mean_kernel(const u16* __restrict__ actR, float* __restrict__ out) {
    __shared__ float2 red[8][64];
    const int tid = threadIdx.x;
    const int g = (blockIdx.x & 7) * 16 + (blockIdx.x >> 3);
    const int cp = tid & 63, lq8 = tid >> 6;
    const unsigned* x32 = (const unsigned*)(actR + (size_t)g * (SEQ * HID));
    float s0 = 0.f, s1 = 0.f;
#pragma unroll
    for (int j = 0; j < 64; ++j) {
        unsigned v = x32[(size_t)(lq8 * 64 + j) * 64 + cp];
        s0 += b2f((u16)(v & 0xffff));
        s1 += b2f((u16)(v >> 16));
    }
    red[lq8][cp] = make_float2(s0, s1);
    __syncthreads();
    if (tid < 64) {
        float a = 0.f, b = 0.f;
#pragma unroll
        for (int j = 0; j < 8; ++j) { float2 v = red[j][tid]; a += v.x; b += v.y; }
        *(float2*)(out + (size_t)g * HID + 2 * tid) =
            make_float2(a * (1.0f / 512.0f), b * (1.0f / 512.0f));
    }
}

extern "C" void kernel_launch(void* const* d_in, const int* in_sizes, int n_in,
                              void* d_out, int out_size, void* d_ws, size_t ws_size,
                              hipStream_t stream) {
    const float* x       = (const float*)d_in[0];
    const float* Wp      = (const float*)d_in[2];
    const float* bp      = (const float*)d_in[3];
    const float* log_tau = (const float*)d_in[4];
    const float* Wi      = (const float*)d_in[5];
    const float* bi      = (const float*)d_in[6];
    const float* Wo      = (const float*)d_in[7];
    const float* bo      = (const float*)d_in[8];
    const float* gm      = (const float*)d_in[9];
    const float* bt      = (const float*)d_in[10];
    float* out = (float*)d_out;

    char* ws = (char*)d_ws;
    const size_t ACT_BYTES = (size_t)NROWS * HID * 2;        // 16 MB each
    u16* actA   = (u16*)(ws);
    u16* actB   = (u16*)(ws + ACT_BYTES);
    float* Pre  = (float*)(ws + 2 * ACT_BYTES);              // 128*64*128*4 = 4 MB
    char* wbase = ws + 2 * ACT_BYTES + (size_t)NG * 64 * HID * 4;
    float4* tab = (float4*)wbase;                            // 3*128*16 = 6144 B (16B-aligned)
    u16* Wibf = (u16*)(wbase + 6144);
    u16* Wobf = Wibf + (size_t)3 * 2 * HID * HID;
    u16* Wpbf = Wobf + (size_t)3 * HID * HID;

    prep_kernel<<<128, 256, 0, stream>>>(Wp, Wi, Wo, log_tau, Wpbf, Wibf, Wobf, tab);
    proj_kernel<<<NROWS / 64, 256, 0, stream>>>(x, Wpbf, bp, actA);

    u16* cur = actA, *nxt = actB;
    for (int d = 0; d < 3; ++d) {
        chunkh_kernel<<<NG, 512, 0, stream>>>(cur, Pre, tab + (size_t)d * HID);
        fused_kernel<<<NG * 8, 512, 0, stream>>>(cur, Pre,
            Wibf + (size_t)d * 2 * HID * HID, Wobf + (size_t)d * HID * HID,
            bi + d * 2 * HID, bo + d * HID, gm + d * HID, bt + d * HID,
            tab + (size_t)d * HID, nxt);
        u16* t = cur; cur = nxt; nxt = t;
    }
    mean_kernel<<<NG, 512, 0, stream>>>(cur, out);
}

// Round 17
// 121.090 us; speedup vs baseline: 1.0145x; 1.0145x over previous
//
#include <hip/hip_runtime.h>
#include <stdint.h>
#include <stddef.h>

#define NG 128
#define SEQ 512
#define CIN 64
#define HID 128
#define NROWS (NG*SEQ)   // 65536
#define KLEN 256
#define YS 272           // ylds/ulds row stride (bytes): 256 data + 16 pad (bank skew)

typedef __attribute__((ext_vector_type(8))) short v8s;
typedef __attribute__((ext_vector_type(4))) short v4s;
typedef __attribute__((ext_vector_type(4))) float v4f;
typedef __attribute__((ext_vector_type(2))) unsigned v2u;
typedef unsigned short u16;

__device__ __forceinline__ float b2f(u16 u) {
    union { unsigned int i; float f; } v; v.i = ((unsigned int)u) << 16; return v.f;
}
__device__ __forceinline__ u16 f2b(float f) {
    unsigned int x = __float_as_uint(f);
    unsigned int r = (x + 0x7fffu + ((x >> 16) & 1u)) >> 16;
    return (u16)r;
}
// packed f32x2 -> bf16x2 (RNE), single HW inst
__device__ __forceinline__ unsigned cvtpk(float lo, float hi) {
    unsigned r;
    asm("v_cvt_pk_bf16_f32 %0, %1, %2" : "=v"(r) : "v"(lo), "v"(hi));
    return r;
}
// fast sigmoid: v_rcp instead of IEEE divide (~1 ulp, pre-bf16-quantization; R12-validated)
__device__ __forceinline__ float sigf(float x) {
    return __builtin_amdgcn_rcpf(1.0f + __expf(-x));
}

// ---------------- prep: f32 -> bf16 weights + per-channel tau table ----------------
__global__ void prep_kernel(const float* __restrict__ Wp, const float* __restrict__ Wi,
                            const float* __restrict__ Wo, const float* __restrict__ log_tau,
                            u16* __restrict__ Wpbf, u16* __restrict__ Wibf,
                            u16* __restrict__ Wobf, float4* __restrict__ tab) {
    int stride = gridDim.x * blockDim.x;
    int t0 = blockIdx.x * blockDim.x + threadIdx.x;
    for (int i = t0; i < 3 * 2 * HID * HID; i += stride) Wibf[i] = f2b(Wi[i]);
    for (int i = t0; i < 3 * HID * HID; i += stride) Wobf[i] = f2b(Wo[i]);
    for (int i = t0; i < HID * CIN; i += stride) Wpbf[i] = f2b(Wp[i]);
    if (t0 < 3 * HID) {
        float tau = fmaxf(expf(log_tau[t0]), 0.001f);
        float lq = -(1.0f / tau) * 1.44269504089f;
        float q = exp2f(lq);
        float S = (q < 0.9999999f) ? (1.0f - exp2f(256.0f * lq)) / (1.0f - q) : 256.0f;
        tab[t0] = make_float4(lq, q, exp2f(-lq), 1.0f / (S + 1e-8f));
    }
}

// ---------------- proj: h = x @ Wp^T + bp -> actR[g*512+l][c] (row-major) ----------------
// XCD swizzle: XCD k owns graphs [k*16, (k+1)*16) — matches chunkh/fused/mean.
__global__ __launch_bounds__(256, 4) void proj_kernel(const float* __restrict__ x,
                                                      const u16* __restrict__ Wp,
                                                      const float* __restrict__ bp,
                                                      u16* __restrict__ actR) {
    const int wave = threadIdx.x >> 6, lane = threadIdx.x & 63;
    const int fr = lane & 15, kgrp = lane >> 4;
    const int swz = (blockIdx.x & 7) * 128 + (blockIdx.x >> 3);   // XCD g-affinity
    const int l = swz * 64 + wave * 16 + fr;           // this lane's output row
    const int n0 = kgrp * 4;                           // channel quad base (per nt add nt*16)

    v4f acc[8];
#pragma unroll
    for (int nt = 0; nt < 8; ++nt) acc[nt] = (v4f){0.f, 0.f, 0.f, 0.f};

#pragma unroll
    for (int ks = 0; ks < 2; ++ks) {
        const float* ap = x + (size_t)l * CIN + ks * 32 + kgrp * 8;
        float4 f0 = *(const float4*)ap;
        float4 f1 = *(const float4*)(ap + 4);
        union { unsigned u[4]; v8s s; } bf;
        bf.u[0] = cvtpk(f0.x, f0.y); bf.u[1] = cvtpk(f0.z, f0.w);
        bf.u[2] = cvtpk(f1.x, f1.y); bf.u[3] = cvtpk(f1.z, f1.w);
#pragma unroll
        for (int nt = 0; nt < 8; ++nt) {
            v8s a = *(const v8s*)(Wp + (size_t)(nt * 16 + fr) * CIN + ks * 32 + kgrp * 8);
            acc[nt] = __builtin_amdgcn_mfma_f32_16x16x32_bf16(a, bf.s, acc[nt], 0, 0, 0);
        }
    }
#pragma unroll
    for (int nt = 0; nt < 8; ++nt) {
        const int c = nt * 16 + n0;
        float4 bb = *(const float4*)(bp + c);
        union { unsigned u[2]; v4s s; } pk;
        pk.u[0] = cvtpk(acc[nt][0] + bb.x, acc[nt][1] + bb.y);
        pk.u[1] = cvtpk(acc[nt][2] + bb.z, acc[nt][3] + bb.w);
        *(v4s*)(actR + (size_t)l * HID + c) = pk.s;
    }
}

// ---------------- chunkh: exclusive-prefix carries Pre[g][64][128] ----------------
// XCD swizzle: g = (b&7)*16 + b>>3 — same g-ownership as fused.
__global__ __launch_bounds__(512) void chunkh_kernel(const u16* __restrict__ actR,
                                                     float* __restrict__ Pre,
                                                     const float4* __restrict__ tab) {
    __shared__ float2 t8[8][64];
    const int tid = threadIdx.x;
    const int g = (blockIdx.x & 7) * 16 + (blockIdx.x >> 3);
    const int cp = tid & 63, sc = tid >> 6;
    const int c0 = 2 * cp;
    const unsigned* x32 = (const unsigned*)(actR + (size_t)g * (SEQ * HID));
    float4 tv0 = tab[c0], tv1 = tab[c0 + 1];
    float q0 = tv0.y, q1 = tv1.y;
    float sp0 = exp2f((float)(sc * 64) * tv0.x);
    float sp1 = exp2f((float)(sc * 64) * tv1.x);
    float h0[8], h1[8];
#pragma unroll
    for (int s = 0; s < 8; ++s) {
        float a0 = 0.f, a1 = 0.f;
#pragma unroll
        for (int j = 0; j < 8; ++j) {
            unsigned xv = x32[(size_t)(sc * 64 + s * 8 + j) * 64 + cp];
            a0 += sp0 * b2f((u16)(xv & 0xffff));
            a1 += sp1 * b2f((u16)(xv >> 16));
            sp0 *= q0; sp1 *= q1;
        }
        h0[s] = a0; h1[s] = a1;
    }
    float T0 = 0.f, T1 = 0.f;
#pragma unroll
    for (int s = 0; s < 8; ++s) { T0 += h0[s]; T1 += h1[s]; }
    t8[sc][cp] = make_float2(T0, T1);
    __syncthreads();
    float b0 = 0.f, b1 = 0.f;
    for (int s = 0; s < sc; ++s) { float2 v = t8[s][cp]; b0 += v.x; b1 += v.y; }
    float* PreG = Pre + (size_t)g * 64 * HID;
#pragma unroll
    for (int s = 0; s < 8; ++s) {
        *(float2*)(PreG + (size_t)(sc * 8 + s) * HID + c0) = make_float2(b0, b1);
        b0 += h0[s]; b1 += h1[s];
    }
}

// ---------------- fused: scan -> GEMM1/GLU -> GEMM2 -> LN -> actR ----------------
// XCD swizzle: XCD k owns all 8 tiles of graphs [k*16, (k+1)*16) -> actR[g]/Pre[g] L2-resident.
__global__ __launch_bounds__(512, 4) void fused_kernel(const u16* __restrict__ actR,
                                                       const float* __restrict__ Pre,
                                                       const u16* __restrict__ Win,
                                                       const u16* __restrict__ Wout,
                                                       const float* __restrict__ b_in,
                                                       const float* __restrict__ b_out,
                                                       const float* __restrict__ gamma,
                                                       const float* __restrict__ beta,
                                                       const float4* __restrict__ tab,
                                                       u16* __restrict__ actRout) {
    __shared__ __align__(16) char ylds[64 * YS];   // y, [l][c] bf16, XOR-swizzled, padded stride
    __shared__ __align__(16) char ulds[64 * YS];   // u, same layout
    __shared__ float2 red[8][64];
    __shared__ float2 murstd[64];
    const int tid = threadIdx.x;
    const int swz = (blockIdx.x & 7) * 128 + (blockIdx.x >> 3);   // XCD g-affinity
    const int g = swz >> 3, tile = swz & 7;
    const int r0 = tile * 64;
    const size_t gbase = (size_t)g * (SEQ * HID);

    // ---- scan: thread (cp, sc) -> channels {2cp,2cp+1}, rows [r0+sc*8, +8) ----
    {
        const int cp = tid & 63, sc = tid >> 6;
        const int c0 = 2 * cp;
        const int l0 = r0 + sc * 8;
        const bool hasd = (r0 >= KLEN);            // block-uniform
        const unsigned* x32 = (const unsigned*)(actR + gbase);
        unsigned xw[8], xdw[8];
#pragma unroll
        for (int j = 0; j < 8; ++j) xw[j] = x32[(size_t)(l0 + j) * 64 + cp];
        if (hasd) {
#pragma unroll
            for (int j = 0; j < 8; ++j) xdw[j] = x32[(size_t)(l0 - KLEN + j) * 64 + cp];
        }
        const float* PreG = Pre + ((size_t)g * 64 + (l0 >> 3)) * HID + c0;
        float2 pin = *(const float2*)PreG;
        float2 pdin = hasd ? *(const float2*)(PreG - 32 * HID) : make_float2(0.f, 0.f);
        float4 tv0 = tab[c0], tv1 = tab[c0 + 1];
        float P[2]    = { pin.x, pin.y };
        float Pd[2]   = { pdin.x, pdin.y };
        float q[2]    = { tv0.y, tv1.y };
        float qinv[2] = { tv0.z, tv1.z };
        float sp[2], w[2], spd[2];
        sp[0] = exp2f((float)l0 * tv0.x);
        sp[1] = exp2f((float)l0 * tv1.x);
        w[0] = exp2f((float)(255 - l0) * tv0.x) * tv0.w;
        w[1] = exp2f((float)(255 - l0) * tv1.x) * tv1.w;
        spd[0] = hasd ? exp2f((float)(l0 - KLEN) * tv0.x) : 0.f;
        spd[1] = hasd ? exp2f((float)(l0 - KLEN) * tv1.x) : 0.f;
#pragma unroll
        for (int j = 0; j < 8; ++j) {
            const int lt = sc * 8 + j;
            float y0, y1;
            {
                P[0] += sp[0] * b2f((u16)(xw[j] & 0xffff)); sp[0] *= q[0];
                P[1] += sp[1] * b2f((u16)(xw[j] >> 16));    sp[1] *= q[1];
                float Po0 = 0.f, Po1 = 0.f;
                if (hasd) {
                    Pd[0] += spd[0] * b2f((u16)(xdw[j] & 0xffff)); spd[0] *= q[0]; Po0 = Pd[0];
                    Pd[1] += spd[1] * b2f((u16)(xdw[j] >> 16));    spd[1] *= q[1]; Po1 = Pd[1];
                }
                y0 = w[0] * (P[0] - Po0); w[0] *= qinv[0];
                y1 = w[1] * (P[1] - Po1); w[1] *= qinv[1];
            }
            *(unsigned*)(ylds + lt * YS + ((4 * cp) ^ ((lt & 7) << 4))) = cvtpk(y0, y1);
        }
    }

    const int wave = tid >> 6, lane = tid & 63;
    const int fr = lane & 15, kgrp = lane >> 4;
    const int n0 = wave * 16 + kgrp * 4;     // this lane's channel quad (GEMM out dim)

    // weight-stationary fragments (A-operands): Win a-rows, g-rows, Wout rows
    v8s b1a[4], b1g[4], b2[4];
#pragma unroll
    for (int ks = 0; ks < 4; ++ks) {
        b1a[ks] = *(const v8s*)(Win + (size_t)(wave * 16 + fr) * HID + ks * 32 + kgrp * 8);
        b1g[ks] = *(const v8s*)(Win + (size_t)((wave + 8) * 16 + fr) * HID + ks * 32 + kgrp * 8);
        b2[ks]  = *(const v8s*)(Wout + (size_t)(wave * 16 + fr) * HID + ks * 32 + kgrp * 8);
    }
    const float4 ba4 = *(const float4*)(b_in + n0);
    const float4 bg4 = *(const float4*)(b_in + HID + n0);
    const float4 bo4 = *(const float4*)(b_out + n0);

    __syncthreads();   // S1: ylds ready

    // ---- GEMM1 swapped (D[n][l]) + in-reg GLU -> ulds b64 packed ----
#pragma unroll
    for (int rt = 0; rt < 4; ++rt) {
        const int arow = rt * 16 + fr;
        const char* abase = ylds + arow * YS;
        const int asw = (arow & 7) << 4;
        v8s af[4];
#pragma unroll
        for (int ks = 0; ks < 4; ++ks)
            af[ks] = *(const v8s*)(abase + ((ks * 64 + kgrp * 16) ^ asw));
        v4f a0 = (v4f){0.f, 0.f, 0.f, 0.f}, a1 = (v4f){0.f, 0.f, 0.f, 0.f};
#pragma unroll
        for (int ks = 0; ks < 4; ++ks) {
            a0 = __builtin_amdgcn_mfma_f32_16x16x32_bf16(b1a[ks], af[ks], a0, 0, 0, 0);
            a1 = __builtin_amdgcn_mfma_f32_16x16x32_bf16(b1g[ks], af[ks], a1, 0, 0, 0);
        }
        float u0 = (a0[0] + ba4.x) * sigf(a1[0] + bg4.x);
        float u1 = (a0[1] + ba4.y) * sigf(a1[1] + bg4.y);
        float u2 = (a0[2] + ba4.z) * sigf(a1[2] + bg4.z);
        float u3 = (a0[3] + ba4.w) * sigf(a1[3] + bg4.w);
        v2u pk;
        pk[0] = cvtpk(u0, u1); pk[1] = cvtpk(u2, u3);
        *(v2u*)(ulds + arow * YS + ((2 * n0) ^ asw)) = pk;
    }
    __syncthreads();   // S2: ulds ready

    // ---- GEMM2 swapped: acc2[rt][r] = z at (n = n0+r, l = rt*16+fr) ----
    v4f acc2[4];
#pragma unroll
    for (int rt = 0; rt < 4; ++rt) acc2[rt] = (v4f){0.f, 0.f, 0.f, 0.f};
#pragma unroll
    for (int rt = 0; rt < 4; ++rt) {
        const int arow = rt * 16 + fr;
        const char* abase = ulds + arow * YS;
        const int asw = (arow & 7) << 4;
#pragma unroll
        for (int ks = 0; ks < 4; ++ks) {
            v8s af = *(const v8s*)(abase + ((ks * 64 + kgrp * 16) ^ asw));
            acc2[rt] = __builtin_amdgcn_mfma_f32_16x16x32_bf16(b2[ks], af, acc2[rt], 0, 0, 0);
        }
    }
    // residual + LN partials (per-lane values are row-aligned now)
#pragma unroll
    for (int rt = 0; rt < 4; ++rt) {
        const int l = rt * 16 + fr;
        v4s yv = *(const v4s*)(ylds + l * YS + ((2 * n0) ^ ((l & 7) << 4)));
        float z0 = acc2[rt][0] + bo4.x + b2f((u16)yv[0]);
        float z1 = acc2[rt][1] + bo4.y + b2f((u16)yv[1]);
        float z2 = acc2[rt][2] + bo4.z + b2f((u16)yv[2]);
        float z3 = acc2[rt][3] + bo4.w + b2f((u16)yv[3]);
        acc2[rt][0] = z0; acc2[rt][1] = z1; acc2[rt][2] = z2; acc2[rt][3] = z3;
        float s = z0 + z1 + z2 + z3;
        float sq = z0 * z0 + z1 * z1 + z2 * z2 + z3 * z3;
        s += __shfl_xor(s, 16); sq += __shfl_xor(sq, 16);
        s += __shfl_xor(s, 32); sq += __shfl_xor(sq, 32);
        if (lane < 16) red[wave][l] = make_float2(s, sq);
    }
    __syncthreads();   // S3: red ready

    if (tid < 64) {
        float a = 0.f, b = 0.f;
#pragma unroll
        for (int j = 0; j < 8; ++j) { float2 v = red[j][tid]; a += v.x; b += v.y; }
        float mu = a * (1.0f / 128.0f);
        float var = b * (1.0f / 128.0f) - mu * mu;
        murstd[tid] = make_float2(mu, rsqrtf(var + 1e-5f));
    }
    __syncthreads();   // S4: murstd ready

    // epilogue: normalize + packed coalesced b64 store to actRout[l][c]
    const float4 gm4 = *(const float4*)(gamma + n0);
    const float4 bt4 = *(const float4*)(beta + n0);
#pragma unroll
    for (int rt = 0; rt < 4; ++rt) {
        const int l = rt * 16 + fr;
        float2 ms = murstd[l];
        float o0 = (acc2[rt][0] - ms.x) * ms.y * gm4.x + bt4.x;
        float o1 = (acc2[rt][1] - ms.x) * ms.y * gm4.y + bt4.y;
        float o2 = (acc2[rt][2] - ms.x) * ms.y * gm4.z + bt4.z;
        float o3 = (acc2[rt][3] - ms.x) * ms.y * gm4.w + bt4.w;
        union { unsigned u[2]; v4s s; } pk;
        pk.u[0] = cvtpk(o0, o1); pk.u[1] = cvtpk(o2, o3);
        *(v4s*)(actRout + gbase + (size_t)(r0 + l) * HID + n0) = pk.s;
    }
}

// ---------------- final mean over L (coalesced [l][c] reads) ----------------
// XCD swizzle: same g-ownership as fused (last layer's actR is L2-hot).
__global__ __launch_bounds__(512) void mean_kernel(const u16* __restrict__ actR, float* __restrict__ out) {
    __shared__ float2 red[8][64];
    const int tid = threadIdx.x;
    const int g = (blockIdx.x & 7) * 16 + (blockIdx.x >> 3);
    const int cp = tid & 63, lq8 = tid >> 6;
    const unsigned* x32 = (const unsigned*)(actR + (size_t)g * (SEQ * HID));
    float s0 = 0.f, s1 = 0.f;
#pragma unroll
    for (int j = 0; j < 64; ++j) {
        unsigned v = x32[(size_t)(lq8 * 64 + j) * 64 + cp];
        s0 += b2f((u16)(v & 0xffff));
        s1 += b2f((u16)(v >> 16));
    }
    red[lq8][cp] = make_float2(s0, s1);
    __syncthreads();
    if (tid < 64) {
        float a = 0.f, b = 0.f;
#pragma unroll
        for (int j = 0; j < 8; ++j) { float2 v = red[j][tid]; a += v.x; b += v.y; }
        *(float2*)(out + (size_t)g * HID + 2 * tid) =
            make_float2(a * (1.0f / 512.0f), b * (1.0f / 512.0f));
    }
}

extern "C" void kernel_launch(void* const* d_in, const int* in_sizes, int n_in,
                              void* d_out, int out_size, void* d_ws, size_t ws_size,
                              hipStream_t stream) {
    const float* x       = (const float*)d_in[0];
    const float* Wp      = (const float*)d_in[2];
    const float* bp      = (const float*)d_in[3];
    const float* log_tau = (const float*)d_in[4];
    const float* Wi      = (const float*)d_in[5];
    const float* bi      = (const float*)d_in[6];
    const float* Wo      = (const float*)d_in[7];
    const float* bo      = (const float*)d_in[8];
    const float* gm      = (const float*)d_in[9];
    const float* bt      = (const float*)d_in[10];
    float* out = (float*)d_out;

    char* ws = (char*)d_ws;
    const size_t ACT_BYTES = (size_t)NROWS * HID * 2;        // 16 MB each
    u16* actA   = (u16*)(ws);
    u16* actB   = (u16*)(ws + ACT_BYTES);
    float* Pre  = (float*)(ws + 2 * ACT_BYTES);              // 128*64*128*4 = 4 MB
    char* wbase = ws + 2 * ACT_BYTES + (size_t)NG * 64 * HID * 4;
    float4* tab = (float4*)wbase;                            // 3*128*16 = 6144 B (16B-aligned)
    u16* Wibf = (u16*)(wbase + 6144);
    u16* Wobf = Wibf + (size_t)3 * 2 * HID * HID;
    u16* Wpbf = Wobf + (size_t)3 * HID * HID;

    prep_kernel<<<128, 256, 0, stream>>>(Wp, Wi, Wo, log_tau, Wpbf, Wibf, Wobf, tab);
    proj_kernel<<<NROWS / 64, 256, 0, stream>>>(x, Wpbf, bp, actA);

    u16* cur = actA, *nxt = actB;
    for (int d = 0; d < 3; ++d) {
        chunkh_kernel<<<NG, 512, 0, stream>>>(cur, Pre, tab + (size_t)d * HID);
        fused_kernel<<<NG * 8, 512, 0, stream>>>(cur, Pre,
            Wibf + (size_t)d * 2 * HID * HID, Wobf + (size_t)d * HID * HID,
            bi + d * 2 * HID, bo + d * HID, gm + d * HID, bt + d * HID,
            tab + (size_t)d * HID, nxt);
        u16* t = cur; cur = nxt; nxt = t;
    }
    mean_kernel<<<NG, 512, 0, stream>>>(cur, out);
}

// Round 18
// 115.903 us; speedup vs baseline: 1.0599x; 1.0448x over previous
//
#include <hip/hip_runtime.h>
#include <stdint.h>
#include <stddef.h>

#define NG 128
#define SEQ 512
#define CIN 64
#define HID 128
#define NROWS (NG*SEQ)   // 65536
#define KLEN 256
#define YS 256           // ylds/ulds row stride (bytes): pure XOR swizzle, uniform bank groups
                         // (YS=272's +4-bank row skew fought the XOR: 16-way pile-up, 4.9M conflict cy)

typedef __attribute__((ext_vector_type(8))) short v8s;
typedef __attribute__((ext_vector_type(4))) short v4s;
typedef __attribute__((ext_vector_type(4))) float v4f;
typedef __attribute__((ext_vector_type(2))) unsigned v2u;
typedef unsigned short u16;

__device__ __forceinline__ float b2f(u16 u) {
    union { unsigned int i; float f; } v; v.i = ((unsigned int)u) << 16; return v.f;
}
__device__ __forceinline__ u16 f2b(float f) {
    unsigned int x = __float_as_uint(f);
    unsigned int r = (x + 0x7fffu + ((x >> 16) & 1u)) >> 16;
    return (u16)r;
}
// packed f32x2 -> bf16x2 (RNE), single HW inst
__device__ __forceinline__ unsigned cvtpk(float lo, float hi) {
    unsigned r;
    asm("v_cvt_pk_bf16_f32 %0, %1, %2" : "=v"(r) : "v"(lo), "v"(hi));
    return r;
}
// fast sigmoid: v_rcp instead of IEEE divide (~1 ulp, pre-bf16-quantization; R12-validated)
__device__ __forceinline__ float sigf(float x) {
    return __builtin_amdgcn_rcpf(1.0f + __expf(-x));
}

// ---------------- prep: f32 -> bf16 weights + per-channel tau table ----------------
__global__ void prep_kernel(const float* __restrict__ Wp, const float* __restrict__ Wi,
                            const float* __restrict__ Wo, const float* __restrict__ log_tau,
                            u16* __restrict__ Wpbf, u16* __restrict__ Wibf,
                            u16* __restrict__ Wobf, float4* __restrict__ tab) {
    int stride = gridDim.x * blockDim.x;
    int t0 = blockIdx.x * blockDim.x + threadIdx.x;
    for (int i = t0; i < 3 * 2 * HID * HID; i += stride) Wibf[i] = f2b(Wi[i]);
    for (int i = t0; i < 3 * HID * HID; i += stride) Wobf[i] = f2b(Wo[i]);
    for (int i = t0; i < HID * CIN; i += stride) Wpbf[i] = f2b(Wp[i]);
    if (t0 < 3 * HID) {
        float tau = fmaxf(expf(log_tau[t0]), 0.001f);
        float lq = -(1.0f / tau) * 1.44269504089f;
        float q = exp2f(lq);
        float S = (q < 0.9999999f) ? (1.0f - exp2f(256.0f * lq)) / (1.0f - q) : 256.0f;
        tab[t0] = make_float4(lq, q, exp2f(-lq), 1.0f / (S + 1e-8f));
    }
}

// ---------------- proj: h = x @ Wp^T + bp -> actR[g*512+l][c] (row-major) ----------------
// XCD swizzle: XCD k owns graphs [k*16, (k+1)*16) — matches chunkh/fused/mean.
__global__ __launch_bounds__(256, 4) void proj_kernel(const float* __restrict__ x,
                                                      const u16* __restrict__ Wp,
                                                      const float* __restrict__ bp,
                                                      u16* __restrict__ actR) {
    const int wave = threadIdx.x >> 6, lane = threadIdx.x & 63;
    const int fr = lane & 15, kgrp = lane >> 4;
    const int swz = (blockIdx.x & 7) * 128 + (blockIdx.x >> 3);   // XCD g-affinity
    const int l = swz * 64 + wave * 16 + fr;           // this lane's output row
    const int n0 = kgrp * 4;                           // channel quad base (per nt add nt*16)

    v4f acc[8];
#pragma unroll
    for (int nt = 0; nt < 8; ++nt) acc[nt] = (v4f){0.f, 0.f, 0.f, 0.f};

#pragma unroll
    for (int ks = 0; ks < 2; ++ks) {
        const float* ap = x + (size_t)l * CIN + ks * 32 + kgrp * 8;
        float4 f0 = *(const float4*)ap;
        float4 f1 = *(const float4*)(ap + 4);
        union { unsigned u[4]; v8s s; } bf;
        bf.u[0] = cvtpk(f0.x, f0.y); bf.u[1] = cvtpk(f0.z, f0.w);
        bf.u[2] = cvtpk(f1.x, f1.y); bf.u[3] = cvtpk(f1.z, f1.w);
#pragma unroll
        for (int nt = 0; nt < 8; ++nt) {
            v8s a = *(const v8s*)(Wp + (size_t)(nt * 16 + fr) * CIN + ks * 32 + kgrp * 8);
            acc[nt] = __builtin_amdgcn_mfma_f32_16x16x32_bf16(a, bf.s, acc[nt], 0, 0, 0);
        }
    }
#pragma unroll
    for (int nt = 0; nt < 8; ++nt) {
        const int c = nt * 16 + n0;
        float4 bb = *(const float4*)(bp + c);
        union { unsigned u[2]; v4s s; } pk;
        pk.u[0] = cvtpk(acc[nt][0] + bb.x, acc[nt][1] + bb.y);
        pk.u[1] = cvtpk(acc[nt][2] + bb.z, acc[nt][3] + bb.w);
        *(v4s*)(actR + (size_t)l * HID + c) = pk.s;
    }
}

// ---------------- chunkh: exclusive-prefix carries Pre[g][64][128] ----------------
// XCD swizzle: g = (b&7)*16 + b>>3 — same g-ownership as fused.
__global__ __launch_bounds__(512) void chunkh_kernel(const u16* __restrict__ actR,
                                                     float* __restrict__ Pre,
                                                     const float4* __restrict__ tab) {
    __shared__ float2 t8[8][64];
    const int tid = threadIdx.x;
    const int g = (blockIdx.x & 7) * 16 + (blockIdx.x >> 3);
    const int cp = tid & 63, sc = tid >> 6;
    const int c0 = 2 * cp;
    const unsigned* x32 = (const unsigned*)(actR + (size_t)g * (SEQ * HID));
    float4 tv0 = tab[c0], tv1 = tab[c0 + 1];
    float q0 = tv0.y, q1 = tv1.y;
    float sp0 = exp2f((float)(sc * 64) * tv0.x);
    float sp1 = exp2f((float)(sc * 64) * tv1.x);
    float h0[8], h1[8];
#pragma unroll
    for (int s = 0; s < 8; ++s) {
        float a0 = 0.f, a1 = 0.f;
#pragma unroll
        for (int j = 0; j < 8; ++j) {
            unsigned xv = x32[(size_t)(sc * 64 + s * 8 + j) * 64 + cp];
            a0 += sp0 * b2f((u16)(xv & 0xffff));
            a1 += sp1 * b2f((u16)(xv >> 16));
            sp0 *= q0; sp1 *= q1;
        }
        h0[s] = a0; h1[s] = a1;
    }
    float T0 = 0.f, T1 = 0.f;
#pragma unroll
    for (int s = 0; s < 8; ++s) { T0 += h0[s]; T1 += h1[s]; }
    t8[sc][cp] = make_float2(T0, T1);
    __syncthreads();
    float b0 = 0.f, b1 = 0.f;
    for (int s = 0; s < sc; ++s) { float2 v = t8[s][cp]; b0 += v.x; b1 += v.y; }
    float* PreG = Pre + (size_t)g * 64 * HID;
#pragma unroll
    for (int s = 0; s < 8; ++s) {
        *(float2*)(PreG + (size_t)(sc * 8 + s) * HID + c0) = make_float2(b0, b1);
        b0 += h0[s]; b1 += h1[s];
    }
}

// ---------------- fused: scan -> GEMM1/GLU -> GEMM2 -> LN -> actR ----------------
// XCD swizzle: XCD k owns all 8 tiles of graphs [k*16, (k+1)*16) -> actR[g]/Pre[g] L2-resident.
__global__ __launch_bounds__(512, 4) void fused_kernel(const u16* __restrict__ actR,
                                                       const float* __restrict__ Pre,
                                                       const u16* __restrict__ Win,
                                                       const u16* __restrict__ Wout,
                                                       const float* __restrict__ b_in,
                                                       const float* __restrict__ b_out,
                                                       const float* __restrict__ gamma,
                                                       const float* __restrict__ beta,
                                                       const float4* __restrict__ tab,
                                                       u16* __restrict__ actRout) {
    __shared__ __align__(16) char ylds[64 * YS];   // y, [l][c] bf16, XOR-swizzled
    __shared__ __align__(16) char ulds[64 * YS];   // u, same layout
    __shared__ float2 red[8][64];
    __shared__ float2 murstd[64];
    const int tid = threadIdx.x;
    const int swz = (blockIdx.x & 7) * 128 + (blockIdx.x >> 3);   // XCD g-affinity
    const int g = swz >> 3, tile = swz & 7;
    const int r0 = tile * 64;
    const size_t gbase = (size_t)g * (SEQ * HID);

    // ---- scan: thread (cp, sc) -> channels {2cp,2cp+1}, rows [r0+sc*8, +8) ----
    {
        const int cp = tid & 63, sc = tid >> 6;
        const int c0 = 2 * cp;
        const int l0 = r0 + sc * 8;
        const bool hasd = (r0 >= KLEN);            // block-uniform
        const unsigned* x32 = (const unsigned*)(actR + gbase);
        unsigned xw[8], xdw[8];
#pragma unroll
        for (int j = 0; j < 8; ++j) xw[j] = x32[(size_t)(l0 + j) * 64 + cp];
        if (hasd) {
#pragma unroll
            for (int j = 0; j < 8; ++j) xdw[j] = x32[(size_t)(l0 - KLEN + j) * 64 + cp];
        }
        const float* PreG = Pre + ((size_t)g * 64 + (l0 >> 3)) * HID + c0;
        float2 pin = *(const float2*)PreG;
        float2 pdin = hasd ? *(const float2*)(PreG - 32 * HID) : make_float2(0.f, 0.f);
        float4 tv0 = tab[c0], tv1 = tab[c0 + 1];
        float P[2]    = { pin.x, pin.y };
        float Pd[2]   = { pdin.x, pdin.y };
        float q[2]    = { tv0.y, tv1.y };
        float qinv[2] = { tv0.z, tv1.z };
        float sp[2], w[2], spd[2];
        sp[0] = exp2f((float)l0 * tv0.x);
        sp[1] = exp2f((float)l0 * tv1.x);
        w[0] = exp2f((float)(255 - l0) * tv0.x) * tv0.w;
        w[1] = exp2f((float)(255 - l0) * tv1.x) * tv1.w;
        spd[0] = hasd ? exp2f((float)(l0 - KLEN) * tv0.x) : 0.f;
        spd[1] = hasd ? exp2f((float)(l0 - KLEN) * tv1.x) : 0.f;
#pragma unroll
        for (int j = 0; j < 8; ++j) {
            const int lt = sc * 8 + j;
            float y0, y1;
            {
                P[0] += sp[0] * b2f((u16)(xw[j] & 0xffff)); sp[0] *= q[0];
                P[1] += sp[1] * b2f((u16)(xw[j] >> 16));    sp[1] *= q[1];
                float Po0 = 0.f, Po1 = 0.f;
                if (hasd) {
                    Pd[0] += spd[0] * b2f((u16)(xdw[j] & 0xffff)); spd[0] *= q[0]; Po0 = Pd[0];
                    Pd[1] += spd[1] * b2f((u16)(xdw[j] >> 16));    spd[1] *= q[1]; Po1 = Pd[1];
                }
                y0 = w[0] * (P[0] - Po0); w[0] *= qinv[0];
                y1 = w[1] * (P[1] - Po1); w[1] *= qinv[1];
            }
            *(unsigned*)(ylds + lt * YS + ((4 * cp) ^ ((lt & 7) << 4))) = cvtpk(y0, y1);
        }
    }

    const int wave = tid >> 6, lane = tid & 63;
    const int fr = lane & 15, kgrp = lane >> 4;
    const int n0 = wave * 16 + kgrp * 4;     // this lane's channel quad (GEMM out dim)

    // weight-stationary fragments (A-operands): Win a-rows, g-rows, Wout rows
    v8s b1a[4], b1g[4], b2[4];
#pragma unroll
    for (int ks = 0; ks < 4; ++ks) {
        b1a[ks] = *(const v8s*)(Win + (size_t)(wave * 16 + fr) * HID + ks * 32 + kgrp * 8);
        b1g[ks] = *(const v8s*)(Win + (size_t)((wave + 8) * 16 + fr) * HID + ks * 32 + kgrp * 8);
        b2[ks]  = *(const v8s*)(Wout + (size_t)(wave * 16 + fr) * HID + ks * 32 + kgrp * 8);
    }
    const float4 ba4 = *(const float4*)(b_in + n0);
    const float4 bg4 = *(const float4*)(b_in + HID + n0);
    const float4 bo4 = *(const float4*)(b_out + n0);

    __syncthreads();   // S1: ylds ready

    // ---- GEMM1 swapped (D[n][l]) + in-reg GLU -> ulds b64 packed ----
#pragma unroll
    for (int rt = 0; rt < 4; ++rt) {
        const int arow = rt * 16 + fr;
        const char* abase = ylds + arow * YS;
        const int asw = (arow & 7) << 4;
        v8s af[4];
#pragma unroll
        for (int ks = 0; ks < 4; ++ks)
            af[ks] = *(const v8s*)(abase + ((ks * 64 + kgrp * 16) ^ asw));
        v4f a0 = (v4f){0.f, 0.f, 0.f, 0.f}, a1 = (v4f){0.f, 0.f, 0.f, 0.f};
#pragma unroll
        for (int ks = 0; ks < 4; ++ks) {
            a0 = __builtin_amdgcn_mfma_f32_16x16x32_bf16(b1a[ks], af[ks], a0, 0, 0, 0);
            a1 = __builtin_amdgcn_mfma_f32_16x16x32_bf16(b1g[ks], af[ks], a1, 0, 0, 0);
        }
        float u0 = (a0[0] + ba4.x) * sigf(a1[0] + bg4.x);
        float u1 = (a0[1] + ba4.y) * sigf(a1[1] + bg4.y);
        float u2 = (a0[2] + ba4.z) * sigf(a1[2] + bg4.z);
        float u3 = (a0[3] + ba4.w) * sigf(a1[3] + bg4.w);
        v2u pk;
        pk[0] = cvtpk(u0, u1); pk[1] = cvtpk(u2, u3);
        *(v2u*)(ulds + arow * YS + ((2 * n0) ^ asw)) = pk;
    }
    __syncthreads();   // S2: ulds ready

    // ---- GEMM2 swapped: acc2[rt][r] = z at (n = n0+r, l = rt*16+fr) ----
    v4f acc2[4];
#pragma unroll
    for (int rt = 0; rt < 4; ++rt) acc2[rt] = (v4f){0.f, 0.f, 0.f, 0.f};
#pragma unroll
    for (int rt = 0; rt < 4; ++rt) {
        const int arow = rt * 16 + fr;
        const char* abase = ulds + arow * YS;
        const int asw = (arow & 7) << 4;
#pragma unroll
        for (int ks = 0; ks < 4; ++ks) {
            v8s af = *(const v8s*)(abase + ((ks * 64 + kgrp * 16) ^ asw));
            acc2[rt] = __builtin_amdgcn_mfma_f32_16x16x32_bf16(b2[ks], af, acc2[rt], 0, 0, 0);
        }
    }
    // residual + LN partials (per-lane values are row-aligned now)
#pragma unroll
    for (int rt = 0; rt < 4; ++rt) {
        const int l = rt * 16 + fr;
        v4s yv = *(const v4s*)(ylds + l * YS + ((2 * n0) ^ ((l & 7) << 4)));
        float z0 = acc2[rt][0] + bo4.x + b2f((u16)yv[0]);
        float z1 = acc2[rt][1] + bo4.y + b2f((u16)yv[1]);
        float z2 = acc2[rt][2] + bo4.z + b2f((u16)yv[2]);
        float z3 = acc2[rt][3] + bo4.w + b2f((u16)yv[3]);
        acc2[rt][0] = z0; acc2[rt][1] = z1; acc2[rt][2] = z2; acc2[rt][3] = z3;
        float s = z0 + z1 + z2 + z3;
        float sq = z0 * z0 + z1 * z1 + z2 * z2 + z3 * z3;
        s += __shfl_xor(s, 16); sq += __shfl_xor(sq, 16);
        s += __shfl_xor(s, 32); sq += __shfl_xor(sq, 32);
        if (lane < 16) red[wave][l] = make_float2(s, sq);
    }
    __syncthreads();   // S3: red ready

    if (tid < 64) {
        float a = 0.f, b = 0.f;
#pragma unroll
        for (int j = 0; j < 8; ++j) { float2 v = red[j][tid]; a += v.x; b += v.y; }
        float mu = a * (1.0f / 128.0f);
        float var = b * (1.0f / 128.0f) - mu * mu;
        murstd[tid] = make_float2(mu, rsqrtf(var + 1e-5f));
    }
    __syncthreads();   // S4: murstd ready

    // epilogue: normalize + packed coalesced b64 store to actRout[l][c]
    const float4 gm4 = *(const float4*)(gamma + n0);
    const float4 bt4 = *(const float4*)(beta + n0);
#pragma unroll
    for (int rt = 0; rt < 4; ++rt) {
        const int l = rt * 16 + fr;
        float2 ms = murstd[l];
        float o0 = (acc2[rt][0] - ms.x) * ms.y * gm4.x + bt4.x;
        float o1 = (acc2[rt][1] - ms.x) * ms.y * gm4.y + bt4.y;
        float o2 = (acc2[rt][2] - ms.x) * ms.y * gm4.z + bt4.z;
        float o3 = (acc2[rt][3] - ms.x) * ms.y * gm4.w + bt4.w;
        union { unsigned u[2]; v4s s; } pk;
        pk.u[0] = cvtpk(o0, o1); pk.u[1] = cvtpk(o2, o3);
        *(v4s*)(actRout + gbase + (size_t)(r0 + l) * HID + n0) = pk.s;
    }
}

// ---------------- final mean over L (coalesced [l][c] reads) ----------------
// XCD swizzle: same g-ownership as fused (last layer's actR is L2-hot).
__global__ __launch_bounds__(512) void mean_kernel(const u16* __restrict__ actR, float* __restrict__ out) {
    __shared__ float2 red[8][64];
    const int tid = threadIdx.x;
    const int g = (blockIdx.x & 7) * 16 + (blockIdx.x >> 3);
    const int cp = tid & 63, lq8 = tid >> 6;
    const unsigned* x32 = (const unsigned*)(actR + (size_t)g * (SEQ * HID));
    float s0 = 0.f, s1 = 0.f;
#pragma unroll
    for (int j = 0; j < 64; ++j) {
        unsigned v = x32[(size_t)(lq8 * 64 + j) * 64 + cp];
        s0 += b2f((u16)(v & 0xffff));
        s1 += b2f((u16)(v >> 16));
    }
    red[lq8][cp] = make_float2(s0, s1);
    __syncthreads();
    if (tid < 64) {
        float a = 0.f, b = 0.f;
#pragma unroll
        for (int j = 0; j < 8; ++j) { float2 v = red[j][tid]; a += v.x; b += v.y; }
        *(float2*)(out + (size_t)g * HID + 2 * tid) =
            make_float2(a * (1.0f / 512.0f), b * (1.0f / 512.0f));
    }
}

extern "C" void kernel_launch(void* const* d_in, const int* in_sizes, int n_in,
                              void* d_out, int out_size, void* d_ws, size_t ws_size,
                              hipStream_t stream) {
    const float* x       = (const float*)d_in[0];
    const float* Wp      = (const float*)d_in[2];
    const float* bp      = (const float*)d_in[3];
    const float* log_tau = (const float*)d_in[4];
    const float* Wi      = (const float*)d_in[5];
    const float* bi      = (const float*)d_in[6];
    const float* Wo      = (const float*)d_in[7];
    const float* bo      = (const float*)d_in[8];
    const float* gm      = (const float*)d_in[9];
    const float* bt      = (const float*)d_in[10];
    float* out = (float*)d_out;

    char* ws = (char*)d_ws;
    const size_t ACT_BYTES = (size_t)NROWS * HID * 2;        // 16 MB each
    u16* actA   = (u16*)(ws);
    u16* actB   = (u16*)(ws + ACT_BYTES);
    float* Pre  = (float*)(ws + 2 * ACT_BYTES);              // 128*64*128*4 = 4 MB
    char* wbase = ws + 2 * ACT_BYTES + (size_t)NG * 64 * HID * 4;
    float4* tab = (float4*)wbase;                            // 3*128*16 = 6144 B (16B-aligned)
    u16* Wibf = (u16*)(wbase + 6144);
    u16* Wobf = Wibf + (size_t)3 * 2 * HID * HID;
    u16* Wpbf = Wobf + (size_t)3 * HID * HID;

    prep_kernel<<<128, 256, 0, stream>>>(Wp, Wi, Wo, log_tau, Wpbf, Wibf, Wobf, tab);
    proj_kernel<<<NROWS / 64, 256, 0, stream>>>(x, Wpbf, bp, actA);

    u16* cur = actA, *nxt = actB;
    for (int d = 0; d < 3; ++d) {
        chunkh_kernel<<<NG, 512, 0, stream>>>(cur, Pre, tab + (size_t)d * HID);
        fused_kernel<<<NG * 8, 512, 0, stream>>>(cur, Pre,
            Wibf + (size_t)d * 2 * HID * HID, Wobf + (size_t)d * HID * HID,
            bi + d * 2 * HID, bo + d * HID, gm + d * HID, bt + d * HID,
            tab + (size_t)d * HID, nxt);
        u16* t = cur; cur = nxt; nxt = t;
    }
    mean_kernel<<<NG, 512, 0, stream>>>(cur, out);
}

// Round 19
// 115.143 us; speedup vs baseline: 1.0669x; 1.0066x over previous
//
#include <hip/hip_runtime.h>
#include <stdint.h>
#include <stddef.h>

#define NG 128
#define SEQ 512
#define CIN 64
#define HID 128
#define NROWS (NG*SEQ)   // 65536
#define KLEN 256
#define YS 256           // ylds/ulds row stride (bytes): pure XOR swizzle, uniform bank groups
                         // (YS=272's +4-bank row skew fought the XOR: 16-way pile-up, 4.9M conflict cy)

typedef __attribute__((ext_vector_type(8))) short v8s;
typedef __attribute__((ext_vector_type(4))) short v4s;
typedef __attribute__((ext_vector_type(4))) float v4f;
typedef __attribute__((ext_vector_type(2))) unsigned v2u;
typedef unsigned short u16;

__device__ __forceinline__ float b2f(u16 u) {
    union { unsigned int i; float f; } v; v.i = ((unsigned int)u) << 16; return v.f;
}
__device__ __forceinline__ u16 f2b(float f) {
    unsigned int x = __float_as_uint(f);
    unsigned int r = (x + 0x7fffu + ((x >> 16) & 1u)) >> 16;
    return (u16)r;
}
// packed f32x2 -> bf16x2 (RNE), single HW inst
__device__ __forceinline__ unsigned cvtpk(float lo, float hi) {
    unsigned r;
    asm("v_cvt_pk_bf16_f32 %0, %1, %2" : "=v"(r) : "v"(lo), "v"(hi));
    return r;
}
// raw v_exp_f32 (R7-validated at absmax 0.015625; args here are in [-355, 0], no range issues)
__device__ __forceinline__ float exp2a(float x) {
#if __has_builtin(__builtin_amdgcn_exp2f)
    return __builtin_amdgcn_exp2f(x);
#else
    float r;
    asm("v_exp_f32 %0, %1\n\ts_nop 1" : "=v"(r) : "v"(x));
    return r;
#endif
}
// fast sigmoid: v_rcp instead of IEEE divide (~1 ulp, pre-bf16-quantization; R12-validated)
__device__ __forceinline__ float sigf(float x) {
    return __builtin_amdgcn_rcpf(1.0f + __expf(-x));
}

// ---------------- prep: f32 -> bf16 weights + per-channel tau table ----------------
// (keeps libm exp2f: runs once; tab stays bit-identical to the validated path)
__global__ void prep_kernel(const float* __restrict__ Wp, const float* __restrict__ Wi,
                            const float* __restrict__ Wo, const float* __restrict__ log_tau,
                            u16* __restrict__ Wpbf, u16* __restrict__ Wibf,
                            u16* __restrict__ Wobf, float4* __restrict__ tab) {
    int stride = gridDim.x * blockDim.x;
    int t0 = blockIdx.x * blockDim.x + threadIdx.x;
    for (int i = t0; i < 3 * 2 * HID * HID; i += stride) Wibf[i] = f2b(Wi[i]);
    for (int i = t0; i < 3 * HID * HID; i += stride) Wobf[i] = f2b(Wo[i]);
    for (int i = t0; i < HID * CIN; i += stride) Wpbf[i] = f2b(Wp[i]);
    if (t0 < 3 * HID) {
        float tau = fmaxf(expf(log_tau[t0]), 0.001f);
        float lq = -(1.0f / tau) * 1.44269504089f;
        float q = exp2f(lq);
        float S = (q < 0.9999999f) ? (1.0f - exp2f(256.0f * lq)) / (1.0f - q) : 256.0f;
        tab[t0] = make_float4(lq, q, exp2f(-lq), 1.0f / (S + 1e-8f));
    }
}

// ---------------- proj: h = x @ Wp^T + bp -> actR[g*512+l][c] (row-major) ----------------
// XCD swizzle: XCD k owns graphs [k*16, (k+1)*16) — matches chunkh/fused/mean.
__global__ __launch_bounds__(256, 4) void proj_kernel(const float* __restrict__ x,
                                                      const u16* __restrict__ Wp,
                                                      const float* __restrict__ bp,
                                                      u16* __restrict__ actR) {
    const int wave = threadIdx.x >> 6, lane = threadIdx.x & 63;
    const int fr = lane & 15, kgrp = lane >> 4;
    const int swz = (blockIdx.x & 7) * 128 + (blockIdx.x >> 3);   // XCD g-affinity
    const int l = swz * 64 + wave * 16 + fr;           // this lane's output row
    const int n0 = kgrp * 4;                           // channel quad base (per nt add nt*16)

    v4f acc[8];
#pragma unroll
    for (int nt = 0; nt < 8; ++nt) acc[nt] = (v4f){0.f, 0.f, 0.f, 0.f};

#pragma unroll
    for (int ks = 0; ks < 2; ++ks) {
        const float* ap = x + (size_t)l * CIN + ks * 32 + kgrp * 8;
        float4 f0 = *(const float4*)ap;
        float4 f1 = *(const float4*)(ap + 4);
        union { unsigned u[4]; v8s s; } bf;
        bf.u[0] = cvtpk(f0.x, f0.y); bf.u[1] = cvtpk(f0.z, f0.w);
        bf.u[2] = cvtpk(f1.x, f1.y); bf.u[3] = cvtpk(f1.z, f1.w);
#pragma unroll
        for (int nt = 0; nt < 8; ++nt) {
            v8s a = *(const v8s*)(Wp + (size_t)(nt * 16 + fr) * CIN + ks * 32 + kgrp * 8);
            acc[nt] = __builtin_amdgcn_mfma_f32_16x16x32_bf16(a, bf.s, acc[nt], 0, 0, 0);
        }
    }
#pragma unroll
    for (int nt = 0; nt < 8; ++nt) {
        const int c = nt * 16 + n0;
        float4 bb = *(const float4*)(bp + c);
        union { unsigned u[2]; v4s s; } pk;
        pk.u[0] = cvtpk(acc[nt][0] + bb.x, acc[nt][1] + bb.y);
        pk.u[1] = cvtpk(acc[nt][2] + bb.z, acc[nt][3] + bb.w);
        *(v4s*)(actR + (size_t)l * HID + c) = pk.s;
    }
}

// ---------------- chunkh: exclusive-prefix carries Pre[g][64][128] ----------------
// XCD swizzle: g = (b&7)*16 + b>>3 — same g-ownership as fused.
__global__ __launch_bounds__(512) void chunkh_kernel(const u16* __restrict__ actR,
                                                     float* __restrict__ Pre,
                                                     const float4* __restrict__ tab) {
    __shared__ float2 t8[8][64];
    const int tid = threadIdx.x;
    const int g = (blockIdx.x & 7) * 16 + (blockIdx.x >> 3);
    const int cp = tid & 63, sc = tid >> 6;
    const int c0 = 2 * cp;
    const unsigned* x32 = (const unsigned*)(actR + (size_t)g * (SEQ * HID));
    float4 tv0 = tab[c0], tv1 = tab[c0 + 1];
    float q0 = tv0.y, q1 = tv1.y;
    float sp0 = exp2a((float)(sc * 64) * tv0.x);
    float sp1 = exp2a((float)(sc * 64) * tv1.x);
    float h0[8], h1[8];
#pragma unroll
    for (int s = 0; s < 8; ++s) {
        float a0 = 0.f, a1 = 0.f;
#pragma unroll
        for (int j = 0; j < 8; ++j) {
            unsigned xv = x32[(size_t)(sc * 64 + s * 8 + j) * 64 + cp];
            a0 += sp0 * b2f((u16)(xv & 0xffff));
            a1 += sp1 * b2f((u16)(xv >> 16));
            sp0 *= q0; sp1 *= q1;
        }
        h0[s] = a0; h1[s] = a1;
    }
    float T0 = 0.f, T1 = 0.f;
#pragma unroll
    for (int s = 0; s < 8; ++s) { T0 += h0[s]; T1 += h1[s]; }
    t8[sc][cp] = make_float2(T0, T1);
    __syncthreads();
    float b0 = 0.f, b1 = 0.f;
    for (int s = 0; s < sc; ++s) { float2 v = t8[s][cp]; b0 += v.x; b1 += v.y; }
    float* PreG = Pre + (size_t)g * 64 * HID;
#pragma unroll
    for (int s = 0; s < 8; ++s) {
        *(float2*)(PreG + (size_t)(sc * 8 + s) * HID + c0) = make_float2(b0, b1);
        b0 += h0[s]; b1 += h1[s];
    }
}

// ---------------- fused: scan -> GEMM1/GLU -> GEMM2 -> LN -> actR ----------------
// XCD swizzle: XCD k owns all 8 tiles of graphs [k*16, (k+1)*16) -> actR[g]/Pre[g] L2-resident.
__global__ __launch_bounds__(512, 4) void fused_kernel(const u16* __restrict__ actR,
                                                       const float* __restrict__ Pre,
                                                       const u16* __restrict__ Win,
                                                       const u16* __restrict__ Wout,
                                                       const float* __restrict__ b_in,
                                                       const float* __restrict__ b_out,
                                                       const float* __restrict__ gamma,
                                                       const float* __restrict__ beta,
                                                       const float4* __restrict__ tab,
                                                       u16* __restrict__ actRout) {
    __shared__ __align__(16) char ylds[64 * YS];   // y, [l][c] bf16, XOR-swizzled
    __shared__ __align__(16) char ulds[64 * YS];   // u, same layout
    __shared__ float2 red[8][64];
    __shared__ float2 murstd[64];
    const int tid = threadIdx.x;
    const int swz = (blockIdx.x & 7) * 128 + (blockIdx.x >> 3);   // XCD g-affinity
    const int g = swz >> 3, tile = swz & 7;
    const int r0 = tile * 64;
    const size_t gbase = (size_t)g * (SEQ * HID);

    // ---- scan: thread (cp, sc) -> channels {2cp,2cp+1}, rows [r0+sc*8, +8) ----
    {
        const int cp = tid & 63, sc = tid >> 6;
        const int c0 = 2 * cp;
        const int l0 = r0 + sc * 8;
        const bool hasd = (r0 >= KLEN);            // block-uniform
        const unsigned* x32 = (const unsigned*)(actR + gbase);
        unsigned xw[8], xdw[8];
#pragma unroll
        for (int j = 0; j < 8; ++j) xw[j] = x32[(size_t)(l0 + j) * 64 + cp];
        if (hasd) {
#pragma unroll
            for (int j = 0; j < 8; ++j) xdw[j] = x32[(size_t)(l0 - KLEN + j) * 64 + cp];
        }
        const float* PreG = Pre + ((size_t)g * 64 + (l0 >> 3)) * HID + c0;
        float2 pin = *(const float2*)PreG;
        float2 pdin = hasd ? *(const float2*)(PreG - 32 * HID) : make_float2(0.f, 0.f);
        float4 tv0 = tab[c0], tv1 = tab[c0 + 1];
        float P[2]    = { pin.x, pin.y };
        float Pd[2]   = { pdin.x, pdin.y };
        float q[2]    = { tv0.y, tv1.y };
        float qinv[2] = { tv0.z, tv1.z };
        float sp[2], w[2], spd[2];
        sp[0] = exp2a((float)l0 * tv0.x);
        sp[1] = exp2a((float)l0 * tv1.x);
        w[0] = exp2a((float)(255 - l0) * tv0.x) * tv0.w;
        w[1] = exp2a((float)(255 - l0) * tv1.x) * tv1.w;
        spd[0] = hasd ? exp2a((float)(l0 - KLEN) * tv0.x) : 0.f;
        spd[1] = hasd ? exp2a((float)(l0 - KLEN) * tv1.x) : 0.f;
#pragma unroll
        for (int j = 0; j < 8; ++j) {
            const int lt = sc * 8 + j;
            float y0, y1;
            {
                P[0] += sp[0] * b2f((u16)(xw[j] & 0xffff)); sp[0] *= q[0];
                P[1] += sp[1] * b2f((u16)(xw[j] >> 16));    sp[1] *= q[1];
                float Po0 = 0.f, Po1 = 0.f;
                if (hasd) {
                    Pd[0] += spd[0] * b2f((u16)(xdw[j] & 0xffff)); spd[0] *= q[0]; Po0 = Pd[0];
                    Pd[1] += spd[1] * b2f((u16)(xdw[j] >> 16));    spd[1] *= q[1]; Po1 = Pd[1];
                }
                y0 = w[0] * (P[0] - Po0); w[0] *= qinv[0];
                y1 = w[1] * (P[1] - Po1); w[1] *= qinv[1];
            }
            *(unsigned*)(ylds + lt * YS + ((4 * cp) ^ ((lt & 7) << 4))) = cvtpk(y0, y1);
        }
    }

    const int wave = tid >> 6, lane = tid & 63;
    const int fr = lane & 15, kgrp = lane >> 4;
    const int n0 = wave * 16 + kgrp * 4;     // this lane's channel quad (GEMM out dim)

    // weight-stationary fragments (A-operands): Win a-rows, g-rows, Wout rows
    v8s b1a[4], b1g[4], b2[4];
#pragma unroll
    for (int ks = 0; ks < 4; ++ks) {
        b1a[ks] = *(const v8s*)(Win + (size_t)(wave * 16 + fr) * HID + ks * 32 + kgrp * 8);
        b1g[ks] = *(const v8s*)(Win + (size_t)((wave + 8) * 16 + fr) * HID + ks * 32 + kgrp * 8);
        b2[ks]  = *(const v8s*)(Wout + (size_t)(wave * 16 + fr) * HID + ks * 32 + kgrp * 8);
    }
    const float4 ba4 = *(const float4*)(b_in + n0);
    const float4 bg4 = *(const float4*)(b_in + HID + n0);
    const float4 bo4 = *(const float4*)(b_out + n0);

    __syncthreads();   // S1: ylds ready

    // ---- GEMM1 swapped (D[n][l]) + in-reg GLU -> ulds b64 packed ----
#pragma unroll
    for (int rt = 0; rt < 4; ++rt) {
        const int arow = rt * 16 + fr;
        const char* abase = ylds + arow * YS;
        const int asw = (arow & 7) << 4;
        v8s af[4];
#pragma unroll
        for (int ks = 0; ks < 4; ++ks)
            af[ks] = *(const v8s*)(abase + ((ks * 64 + kgrp * 16) ^ asw));
        v4f a0 = (v4f){0.f, 0.f, 0.f, 0.f}, a1 = (v4f){0.f, 0.f, 0.f, 0.f};
#pragma unroll
        for (int ks = 0; ks < 4; ++ks) {
            a0 = __builtin_amdgcn_mfma_f32_16x16x32_bf16(b1a[ks], af[ks], a0, 0, 0, 0);
            a1 = __builtin_amdgcn_mfma_f32_16x16x32_bf16(b1g[ks], af[ks], a1, 0, 0, 0);
        }
        float u0 = (a0[0] + ba4.x) * sigf(a1[0] + bg4.x);
        float u1 = (a0[1] + ba4.y) * sigf(a1[1] + bg4.y);
        float u2 = (a0[2] + ba4.z) * sigf(a1[2] + bg4.z);
        float u3 = (a0[3] + ba4.w) * sigf(a1[3] + bg4.w);
        v2u pk;
        pk[0] = cvtpk(u0, u1); pk[1] = cvtpk(u2, u3);
        *(v2u*)(ulds + arow * YS + ((2 * n0) ^ asw)) = pk;
    }
    __syncthreads();   // S2: ulds ready

    // ---- GEMM2 swapped: acc2[rt][r] = z at (n = n0+r, l = rt*16+fr) ----
    v4f acc2[4];
#pragma unroll
    for (int rt = 0; rt < 4; ++rt) acc2[rt] = (v4f){0.f, 0.f, 0.f, 0.f};
#pragma unroll
    for (int rt = 0; rt < 4; ++rt) {
        const int arow = rt * 16 + fr;
        const char* abase = ulds + arow * YS;
        const int asw = (arow & 7) << 4;
#pragma unroll
        for (int ks = 0; ks < 4; ++ks) {
            v8s af = *(const v8s*)(abase + ((ks * 64 + kgrp * 16) ^ asw));
            acc2[rt] = __builtin_amdgcn_mfma_f32_16x16x32_bf16(b2[ks], af, acc2[rt], 0, 0, 0);
        }
    }
    // residual + LN partials (per-lane values are row-aligned now)
#pragma unroll
    for (int rt = 0; rt < 4; ++rt) {
        const int l = rt * 16 + fr;
        v4s yv = *(const v4s*)(ylds + l * YS + ((2 * n0) ^ ((l & 7) << 4)));
        float z0 = acc2[rt][0] + bo4.x + b2f((u16)yv[0]);
        float z1 = acc2[rt][1] + bo4.y + b2f((u16)yv[1]);
        float z2 = acc2[rt][2] + bo4.z + b2f((u16)yv[2]);
        float z3 = acc2[rt][3] + bo4.w + b2f((u16)yv[3]);
        acc2[rt][0] = z0; acc2[rt][1] = z1; acc2[rt][2] = z2; acc2[rt][3] = z3;
        float s = z0 + z1 + z2 + z3;
        float sq = z0 * z0 + z1 * z1 + z2 * z2 + z3 * z3;
        s += __shfl_xor(s, 16); sq += __shfl_xor(sq, 16);
        s += __shfl_xor(s, 32); sq += __shfl_xor(sq, 32);
        if (lane < 16) red[wave][l] = make_float2(s, sq);
    }
    __syncthreads();   // S3: red ready

    if (tid < 64) {
        float a = 0.f, b = 0.f;
#pragma unroll
        for (int j = 0; j < 8; ++j) { float2 v = red[j][tid]; a += v.x; b += v.y; }
        float mu = a * (1.0f / 128.0f);
        float var = b * (1.0f / 128.0f) - mu * mu;
        murstd[tid] = make_float2(mu, rsqrtf(var + 1e-5f));
    }
    __syncthreads();   // S4: murstd ready

    // epilogue: normalize + packed coalesced b64 store to actRout[l][c]
    const float4 gm4 = *(const float4*)(gamma + n0);
    const float4 bt4 = *(const float4*)(beta + n0);
#pragma unroll
    for (int rt = 0; rt < 4; ++rt) {
        const int l = rt * 16 + fr;
        float2 ms = murstd[l];
        float o0 = (acc2[rt][0] - ms.x) * ms.y * gm4.x + bt4.x;
        float o1 = (acc2[rt][1] - ms.x) * ms.y * gm4.y + bt4.y;
        float o2 = (acc2[rt][2] - ms.x) * ms.y * gm4.z + bt4.z;
        float o3 = (acc2[rt][3] - ms.x) * ms.y * gm4.w + bt4.w;
        union { unsigned u[2]; v4s s; } pk;
        pk.u[0] = cvtpk(o0, o1); pk.u[1] = cvtpk(o2, o3);
        *(v4s*)(actRout + gbase + (size_t)(r0 + l) * HID + n0) = pk.s;
    }
}

// ---------------- final mean over L (coalesced [l][c] reads) ----------------
// XCD swizzle: same g-ownership as fused (last layer's actR is L2-hot).
__global__ __launch_bounds__(512) void mean_kernel(const u16* __restrict__ actR, float* __restrict__ out) {
    __shared__ float2 red[8][64];
    const int tid = threadIdx.x;
    const int g = (blockIdx.x & 7) * 16 + (blockIdx.x >> 3);
    const int cp = tid & 63, lq8 = tid >> 6;
    const unsigned* x32 = (const unsigned*)(actR + (size_t)g * (SEQ * HID));
    float s0 = 0.f, s1 = 0.f;
#pragma unroll
    for (int j = 0; j < 64; ++j) {
        unsigned v = x32[(size_t)(lq8 * 64 + j) * 64 + cp];
        s0 += b2f((u16)(v & 0xffff));
        s1 += b2f((u16)(v >> 16));
    }
    red[lq8][cp] = make_float2(s0, s1);
    __syncthreads();
    if (tid < 64) {
        float a = 0.f, b = 0.f;
#pragma unroll
        for (int j = 0; j < 8; ++j) { float2 v = red[j][tid]; a += v.x; b += v.y; }
        *(float2*)(out + (size_t)g * HID + 2 * tid) =
            make_float2(a * (1.0f / 512.0f), b * (1.0f / 512.0f));
    }
}

extern "C" void kernel_launch(void* const* d_in, const int* in_sizes, int n_in,
                              void* d_out, int out_size, void* d_ws, size_t ws_size,
                              hipStream_t stream) {
    const float* x       = (const float*)d_in[0];
    const float* Wp      = (const float*)d_in[2];
    const float* bp      = (const float*)d_in[3];
    const float* log_tau = (const float*)d_in[4];
    const float* Wi      = (const float*)d_in[5];
    const float* bi      = (const float*)d_in[6];
    const float* Wo      = (const float*)d_in[7];
    const float* bo      = (const float*)d_in[8];
    const float* gm      = (const float*)d_in[9];
    const float* bt      = (const float*)d_in[10];
    float* out = (float*)d_out;

    char* ws = (char*)d_ws;
    const size_t ACT_BYTES = (size_t)NROWS * HID * 2;        // 16 MB each
    u16* actA   = (u16*)(ws);
    u16* actB   = (u16*)(ws + ACT_BYTES);
    float* Pre  = (float*)(ws + 2 * ACT_BYTES);              // 128*64*128*4 = 4 MB
    char* wbase = ws + 2 * ACT_BYTES + (size_t)NG * 64 * HID * 4;
    float4* tab = (float4*)wbase;                            // 3*128*16 = 6144 B (16B-aligned)
    u16* Wibf = (u16*)(wbase + 6144);
    u16* Wobf = Wibf + (size_t)3 * 2 * HID * HID;
    u16* Wpbf = Wobf + (size_t)3 * HID * HID;

    prep_kernel<<<128, 256, 0, stream>>>(Wp, Wi, Wo, log_tau, Wpbf, Wibf, Wobf, tab);
    proj_kernel<<<NROWS / 64, 256, 0, stream>>>(x, Wpbf, bp, actA);

    u16* cur = actA, *nxt = actB;
    for (int d = 0; d < 3; ++d) {
        chunkh_kernel<<<NG, 512, 0, stream>>>(cur, Pre, tab + (size_t)d * HID);
        fused_kernel<<<NG * 8, 512, 0, stream>>>(cur, Pre,
            Wibf + (size_t)d * 2 * HID * HID, Wobf + (size_t)d * HID * HID,
            bi + d * 2 * HID, bo + d * HID, gm + d * HID, bt + d * HID,
            tab + (size_t)d * HID, nxt);
        u16* t = cur; cur = nxt; nxt = t;
    }
    mean_kernel<<<NG, 512, 0, stream>>>(cur, out);
}